// Round 13
// baseline (140.360 us; speedup 1.0000x reference)
//
#include <hip/hip_runtime.h>
#include <math.h>

#define BATCH 8192
#define SENTS 50
#define ED    256
#define NENT  20

// log2(200)/256
#define RATE_K 0.0298588132413075f

typedef float f4 __attribute__((ext_vector_type(4)));

// ---------------------------------------------------------------------------
// Fully fused: one block (256 thr = 4 waves) per batch.
//  Phase 1: stream 50 sents rows + 20 ent rows (nt, issued up front).
//           wave r owns rows s = r+4k; lane c owns float4 cols [4c..4c+3].
//  Phase 2: wave-local softmax partials (mr,dr,hacc) -> LDS -> barrier ->
//           LSE merge: thread t owns h[t]; ent partials -> m[t].
//  Phase 3: bilinear in-block: wave r owns A-rows e'=r+4j, lane c reads
//           A[e'][4c..4c+3] (coalesced, L2-resident 256KB), broadcast
//           h_lds[e'] -> acc4. Merge across waves, *m[t], block-reduce,
//           sigmoid, one scalar store. No workspace at all.
// ---------------------------------------------------------------------------
__global__ __launch_bounds__(256) void fused_all_kernel(
    const float* __restrict__ sents, const float* __restrict__ entities,
    const float* __restrict__ A, const float* __restrict__ dense_w,
    const float* __restrict__ dense_b, float* __restrict__ out)
{
    __shared__ __align__(16) float hp[4][ED];     // h partials per wave
    __shared__ __align__(16) float ep[4][ED];     // ent partials per wave
    __shared__ __align__(16) float pp[4][ED];     // bilinear partials per wave
    __shared__ float md[4][2];
    __shared__ float hl[ED];
    __shared__ float ml[ED];
    __shared__ float wred[4];

    int t = threadIdx.x;
    int c = t & 63;
    int r = t >> 6;           // wave id = row residue 0..3
    int b = blockIdx.x;
    bool has13 = (r < 2);     // k=12 row: 48 (r=0), 49 (r=1)

    const f4* s4 = (const f4*)(sents + (size_t)b * SENTS * ED);
    const f4* e4 = (const f4*)(entities + (size_t)b * NENT * ED);

    // ---- Phase 1: issue ALL streaming loads up front (nt) ----
    f4 qv = __builtin_nontemporal_load(&s4[49 * 64 + c]);
    f4 xv[13];
    #pragma unroll
    for (int k = 0; k < 12; ++k)
        xv[k] = __builtin_nontemporal_load(&s4[(r + 4 * k) * 64 + c]);
    if (has13) xv[12] = __builtin_nontemporal_load(&s4[(r + 48) * 64 + c]);
    f4 ev[5];
    #pragma unroll
    for (int n = 0; n < 5; ++n)
        ev[n] = __builtin_nontemporal_load(&e4[(r + 4 * n) * 64 + c]);
    float wt = dense_w[t];

    // ---- per-lane rates (VALU under load latency) ----
    f4 rate;
    rate.x = exp2f(-(float)(4 * c + 0) * RATE_K);
    rate.y = exp2f(-(float)(4 * c + 1) * RATE_K);
    rate.z = exp2f(-(float)(4 * c + 2) * RATE_K);
    rate.w = exp2f(-(float)(4 * c + 3) * RATE_K);

    f4 q;
    q.x = qv.x + __sinf(49.f * rate.x);
    q.y = qv.y + __sinf(49.f * rate.y);
    q.z = qv.z + __sinf(49.f * rate.z);
    q.w = qv.w + __sinf(49.f * rate.w);

    // ---- x = sents + pos; per-row logits via butterfly ----
    f4 x[13];
    float lg[13];
    #pragma unroll
    for (int k = 0; k < 13; ++k) {
        if (k < 12 || has13) {
            float fs = (float)(r + 4 * k);
            x[k].x = xv[k].x + __sinf(fs * rate.x);
            x[k].y = xv[k].y + __sinf(fs * rate.y);
            x[k].z = xv[k].z + __sinf(fs * rate.z);
            x[k].w = xv[k].w + __sinf(fs * rate.w);
            float p = x[k].x * q.x + x[k].y * q.y + x[k].z * q.z + x[k].w * q.w;
            p += __shfl_xor(p, 1);
            p += __shfl_xor(p, 2);
            p += __shfl_xor(p, 4);
            p += __shfl_xor(p, 8);
            p += __shfl_xor(p, 16);
            p += __shfl_xor(p, 32);
            lg[k] = p;
        }
    }

    // ---- wave-local softmax partial ----
    float mr = lg[0];
    #pragma unroll
    for (int k = 1; k < 13; ++k)
        if (k < 12 || has13) mr = fmaxf(mr, lg[k]);

    float dr = 0.f;
    f4 hacc = (f4)0.f;
    #pragma unroll
    for (int k = 0; k < 13; ++k) {
        if (k < 12 || has13) {
            float w = __expf(lg[k] - mr);
            dr += w;
            hacc.x += w * x[k].x; hacc.y += w * x[k].y;
            hacc.z += w * x[k].z; hacc.w += w * x[k].w;
        }
    }

    // ---- entity partial ----
    f4 es;
    es.x = ((ev[0].x + ev[1].x) + (ev[2].x + ev[3].x)) + ev[4].x;
    es.y = ((ev[0].y + ev[1].y) + (ev[2].y + ev[3].y)) + ev[4].y;
    es.z = ((ev[0].z + ev[1].z) + (ev[2].z + ev[3].z)) + ev[4].z;
    es.w = ((ev[0].w + ev[1].w) + (ev[2].w + ev[3].w)) + ev[4].w;

    *(f4*)&hp[r][4 * c] = hacc;
    *(f4*)&ep[r][4 * c] = es;
    if (c == 0) { md[r][0] = mr; md[r][1] = dr; }
    __syncthreads();

    // ---- Phase 2: LSE merge; thread t owns column t ----
    {
        float m0 = md[0][0], d0 = md[0][1];
        float m1 = md[1][0], d1 = md[1][1];
        float m2 = md[2][0], d2 = md[2][1];
        float m3 = md[3][0], d3 = md[3][1];
        float M  = fmaxf(fmaxf(m0, m1), fmaxf(m2, m3));
        float s0 = __expf(m0 - M), s1 = __expf(m1 - M);
        float s2 = __expf(m2 - M), s3 = __expf(m3 - M);
        float dd = s0 * d0 + s1 * d1 + s2 * d2 + s3 * d3;
        float hv = s0 * hp[0][t] + s1 * hp[1][t] + s2 * hp[2][t] + s3 * hp[3][t];
        hl[t] = hv / dd;
        ml[t] = ((ep[0][t] + ep[1][t]) + (ep[2][t] + ep[3][t])) * wt;
    }
    __syncthreads();

    // ---- Phase 3: bilinear. wave r owns A-rows e' = r+4j, j=0..63 ----
    const f4* A4 = (const f4*)A;
    f4 acc = (f4)0.f;
    #pragma unroll 8
    for (int j = 0; j < 64; ++j) {
        int e = r + 4 * j;
        float hs = hl[e];                 // LDS broadcast
        f4 av = A4[e * 64 + c];           // coalesced 1KB/wave, L2-resident
        acc.x += hs * av.x; acc.y += hs * av.y;
        acc.z += hs * av.z; acc.w += hs * av.w;
    }
    *(f4*)&pp[r][4 * c] = acc;
    __syncthreads();

    // ---- final: v[t] = (sum_r pp[r][t]) * m[t]; block-reduce; sigmoid ----
    float v = ((pp[0][t] + pp[1][t]) + (pp[2][t] + pp[3][t])) * ml[t];
    v += __shfl_xor(v, 1);
    v += __shfl_xor(v, 2);
    v += __shfl_xor(v, 4);
    v += __shfl_xor(v, 8);
    v += __shfl_xor(v, 16);
    v += __shfl_xor(v, 32);
    if (c == 0) wred[r] = v;
    __syncthreads();

    if (t == 0) {
        float tot = (wred[0] + wred[1]) + (wred[2] + wred[3]);
        out[b] = 1.f / (1.f + __expf(-(tot + dense_b[0])));
    }
}

extern "C" void kernel_launch(void* const* d_in, const int* in_sizes, int n_in,
                              void* d_out, int out_size, void* d_ws, size_t ws_size,
                              hipStream_t stream) {
    const float* sents    = (const float*)d_in[0];
    const float* entities = (const float*)d_in[1];
    const float* A        = (const float*)d_in[2];
    const float* dense_w  = (const float*)d_in[3];
    const float* dense_b  = (const float*)d_in[4];
    float* out = (float*)d_out;

    fused_all_kernel<<<BATCH, 256, 0, stream>>>(
        sents, entities, A, dense_w, dense_b, out);
}

// Round 14
// 132.901 us; speedup vs baseline: 1.0561x; 1.0561x over previous
//
#include <hip/hip_runtime.h>
#include <math.h>

#define BATCH 8192
#define SENTS 50
#define ED    256
#define NENT  20
#define BB    16

#define SENT_BLOCKS BATCH            // 8192
#define ENT_BLOCKS  (BATCH / 4)      // 2048

// log2(200)/256
#define RATE_K 0.0298588132413075f

typedef float f4 __attribute__((ext_vector_type(4)));

// ---------------------------------------------------------------------------
// Kernel 1 (fat): blocks [0, SENT_BLOCKS) -> h[b] (attention, nt loads);
//                 blocks [SENT_BLOCKS, +ENT_BLOCKS) -> m[b] (ent reduce, nt).
// sents branch: 4 waves; wave r owns rows s=r+4k; per-wave local softmax
// partial (mr, dr, hacc) -> LDS -> ONE barrier -> log-sum-exp merge.
// ---------------------------------------------------------------------------
__global__ __launch_bounds__(256) void fat_kernel(
    const float* __restrict__ sents, const float* __restrict__ entities,
    const float* __restrict__ dense_w,
    float* __restrict__ h_out, float* __restrict__ m_out)
{
    __shared__ __align__(16) float hp[4][ED];
    __shared__ float md[4][2];

    int t = threadIdx.x;

    if (blockIdx.x < SENT_BLOCKS) {
        int b = blockIdx.x;
        int c = t & 63;
        int r = t >> 6;           // wave id = row residue 0..3
        bool has13 = (r < 2);     // k=12 row: 48 (r=0), 49 (r=1)

        const f4* s4 = (const f4*)(sents + (size_t)b * SENTS * ED);

        // ---- issue all loads up front (nt: pure stream) ----
        f4 qv = __builtin_nontemporal_load(&s4[49 * 64 + c]);
        f4 xv[13];
        #pragma unroll
        for (int k = 0; k < 12; ++k)
            xv[k] = __builtin_nontemporal_load(&s4[(r + 4 * k) * 64 + c]);
        if (has13) xv[12] = __builtin_nontemporal_load(&s4[(r + 48) * 64 + c]);

        // ---- per-lane rates (VALU under load latency) ----
        f4 rate;
        rate.x = exp2f(-(float)(4 * c + 0) * RATE_K);
        rate.y = exp2f(-(float)(4 * c + 1) * RATE_K);
        rate.z = exp2f(-(float)(4 * c + 2) * RATE_K);
        rate.w = exp2f(-(float)(4 * c + 3) * RATE_K);

        f4 q;
        q.x = qv.x + __sinf(49.f * rate.x);
        q.y = qv.y + __sinf(49.f * rate.y);
        q.z = qv.z + __sinf(49.f * rate.z);
        q.w = qv.w + __sinf(49.f * rate.w);

        // ---- x = sents + pos; per-row logits via butterfly ----
        f4 x[13];
        float lg[13];
        #pragma unroll
        for (int k = 0; k < 13; ++k) {
            if (k < 12 || has13) {
                float fs = (float)(r + 4 * k);
                x[k].x = xv[k].x + __sinf(fs * rate.x);
                x[k].y = xv[k].y + __sinf(fs * rate.y);
                x[k].z = xv[k].z + __sinf(fs * rate.z);
                x[k].w = xv[k].w + __sinf(fs * rate.w);
                float p = x[k].x * q.x + x[k].y * q.y + x[k].z * q.z + x[k].w * q.w;
                p += __shfl_xor(p, 1);
                p += __shfl_xor(p, 2);
                p += __shfl_xor(p, 4);
                p += __shfl_xor(p, 8);
                p += __shfl_xor(p, 16);
                p += __shfl_xor(p, 32);
                lg[k] = p;
            }
        }

        // ---- wave-local softmax partial ----
        float mr = lg[0];
        #pragma unroll
        for (int k = 1; k < 13; ++k)
            if (k < 12 || has13) mr = fmaxf(mr, lg[k]);

        float dr = 0.f;
        f4 hacc = (f4)0.f;
        #pragma unroll
        for (int k = 0; k < 13; ++k) {
            if (k < 12 || has13) {
                float w = __expf(lg[k] - mr);
                dr += w;
                hacc.x += w * x[k].x; hacc.y += w * x[k].y;
                hacc.z += w * x[k].z; hacc.w += w * x[k].w;
            }
        }

        *(f4*)&hp[r][4 * c] = hacc;
        if (c == 0) { md[r][0] = mr; md[r][1] = dr; }
        __syncthreads();

        // ---- LSE merge across 4 waves; thread t owns column t ----
        float m0 = md[0][0], d0 = md[0][1];
        float m1 = md[1][0], d1 = md[1][1];
        float m2 = md[2][0], d2 = md[2][1];
        float m3 = md[3][0], d3 = md[3][1];
        float M  = fmaxf(fmaxf(m0, m1), fmaxf(m2, m3));
        float s0 = __expf(m0 - M), s1 = __expf(m1 - M);
        float s2 = __expf(m2 - M), s3 = __expf(m3 - M);
        float dd = s0 * d0 + s1 * d1 + s2 * d2 + s3 * d3;
        float hv = s0 * hp[0][t] + s1 * hp[1][t] + s2 * hp[2][t] + s3 * hp[3][t];
        h_out[(size_t)b * ED + t] = hv / dd;
    } else {
        int b = (blockIdx.x - SENT_BLOCKS) * 4 + (t >> 6);
        int c = t & 63;

        const f4* e4 = (const f4*)(entities + (size_t)b * NENT * ED);

        f4 a[NENT];
        #pragma unroll
        for (int n = 0; n < NENT; ++n)
            a[n] = __builtin_nontemporal_load(&e4[n * 64 + c]);

        f4 s = (f4)0.f;
        #pragma unroll
        for (int n = 0; n < NENT; ++n) s += a[n];

        f4 w4 = ((const f4*)dense_w)[c];
        s *= w4;
        ((f4*)(m_out + (size_t)b * ED))[c] = s;
    }
}

// ---------------------------------------------------------------------------
// Kernel 2: out[b] = sigmoid( sum_t (sum_e' h[e'] A[e',t]) * m[t] + bias ).
// BB batches per block; coalesced row reads of A (L2-resident, no transpose).
// ---------------------------------------------------------------------------
__global__ __launch_bounds__(256) void bilinear_kernel(
    const float* __restrict__ hws, const float* __restrict__ mws,
    const float* __restrict__ A, const float* __restrict__ dense_b,
    float* __restrict__ out)
{
    __shared__ __align__(16) float hl[BB][ED];
    __shared__ float ml[BB][ED];
    __shared__ float part[BB][ED];

    int t  = threadIdx.x;
    int b0 = blockIdx.x * BB;

    for (int i = 0; i < BB; ++i) {
        hl[i][t] = hws[(size_t)(b0 + i) * ED + t];
        ml[i][t] = mws[(size_t)(b0 + i) * ED + t];
    }
    __syncthreads();

    float acc[BB];
    #pragma unroll
    for (int i = 0; i < BB; ++i) acc[i] = 0.f;

    for (int ep = 0; ep < ED; ep += 4) {
        float a0 = A[(ep + 0) * ED + t];
        float a1 = A[(ep + 1) * ED + t];
        float a2 = A[(ep + 2) * ED + t];
        float a3 = A[(ep + 3) * ED + t];
        #pragma unroll
        for (int i = 0; i < BB; ++i) {
            float4 hv = *(const float4*)&hl[i][ep];
            acc[i] += hv.x * a0 + hv.y * a1 + hv.z * a2 + hv.w * a3;
        }
    }

    #pragma unroll
    for (int i = 0; i < BB; ++i) part[i][t] = acc[i] * ml[i][t];
    __syncthreads();

    int lane = t & 63, w = t >> 6;
    float bias = dense_b[0];
    for (int i = w; i < BB; i += 4) {
        float v = part[i][lane] + part[i][lane + 64] + part[i][lane + 128] + part[i][lane + 192];
        for (int off = 32; off >= 1; off >>= 1) v += __shfl_xor(v, off);
        if (lane == 0) out[b0 + i] = 1.f / (1.f + __expf(-(v + bias)));
    }
}

// ---------------------------------------------------------------------------
// Fallback: fully fused, no workspace (in case ws_size is tiny)
// ---------------------------------------------------------------------------
__global__ __launch_bounds__(256) void fused_kernel(
    const float* __restrict__ sents, const float* __restrict__ entities,
    const float* __restrict__ A, const float* __restrict__ dense_w,
    const float* __restrict__ dense_b, float* __restrict__ out)
{
    __shared__ __align__(16) float xs[SENTS][ED + 4];
    __shared__ float logit_s[64];
    __shared__ float coef[64];
    __shared__ __align__(16) float harr[ED];
    __shared__ float marr[ED];
    __shared__ float red[4];

    int t    = threadIdx.x;
    int b    = blockIdx.x;
    int lane = t & 63;
    int w    = t >> 6;

    float rate = exp2f(-(float)t * RATE_K);
    const float* sp = sents + (size_t)b * SENTS * ED;
    for (int s = 0; s < SENTS; ++s)
        xs[s][t] = sp[s * ED + t] + sinf((float)s * rate);
    __syncthreads();

    float4 q = *(const float4*)&xs[SENTS - 1][lane * 4];
    for (int s = w; s < SENTS; s += 4) {
        float4 v = *(const float4*)&xs[s][lane * 4];
        float p = v.x * q.x + v.y * q.y + v.z * q.z + v.w * q.w;
        p += __shfl_down(p, 32);
        p += __shfl_down(p, 16);
        p += __shfl_down(p, 8);
        p += __shfl_down(p, 4);
        p += __shfl_down(p, 2);
        p += __shfl_down(p, 1);
        if (lane == 0) logit_s[s] = p;
    }
    __syncthreads();

    if (w == 0) {
        float l = (lane < SENTS) ? logit_s[lane] : -INFINITY;
        float mx = l;
        for (int off = 32; off >= 1; off >>= 1) mx = fmaxf(mx, __shfl_xor(mx, off));
        float ex = (lane < SENTS) ? expf(l - mx) : 0.f;
        float sm = ex;
        for (int off = 32; off >= 1; off >>= 1) sm += __shfl_xor(sm, off);
        if (lane < SENTS) coef[lane] = ex / sm;
    }
    __syncthreads();

    float h = 0.f;
    #pragma unroll
    for (int s = 0; s < SENTS; ++s) h += coef[s] * xs[s][t];

    const float* ent = entities + (size_t)b * NENT * ED;
    float es = 0.f;
    #pragma unroll
    for (int n = 0; n < NENT; ++n) es += ent[n * ED + t];
    float m = es * dense_w[t];

    harr[t] = h;
    marr[t] = m;
    __syncthreads();

    float acc = 0.f;
    for (int ep = 0; ep < ED; ep += 4) {
        float4 hv = *(const float4*)&harr[ep];
        acc += hv.x * A[(ep + 0) * ED + t];
        acc += hv.y * A[(ep + 1) * ED + t];
        acc += hv.z * A[(ep + 2) * ED + t];
        acc += hv.w * A[(ep + 3) * ED + t];
    }
    float val = acc * marr[t];
    val += __shfl_down(val, 32);
    val += __shfl_down(val, 16);
    val += __shfl_down(val, 8);
    val += __shfl_down(val, 4);
    val += __shfl_down(val, 2);
    val += __shfl_down(val, 1);
    if (lane == 0) red[w] = val;
    __syncthreads();
    if (t == 0) {
        float tot = red[0] + red[1] + red[2] + red[3];
        out[b] = 1.f / (1.f + expf(-(tot + dense_b[0])));
    }
}

extern "C" void kernel_launch(void* const* d_in, const int* in_sizes, int n_in,
                              void* d_out, int out_size, void* d_ws, size_t ws_size,
                              hipStream_t stream) {
    const float* sents    = (const float*)d_in[0];
    const float* entities = (const float*)d_in[1];
    const float* A        = (const float*)d_in[2];
    const float* dense_w  = (const float*)d_in[3];
    const float* dense_b  = (const float*)d_in[4];
    float* out = (float*)d_out;

    size_t hm_bytes = (size_t)BATCH * ED * sizeof(float);           // 8 MB each
    size_t need = 2 * hm_bytes;

    if (ws_size >= need) {
        float* hws = (float*)d_ws;
        float* mws = (float*)((char*)d_ws + hm_bytes);
        fat_kernel<<<SENT_BLOCKS + ENT_BLOCKS, 256, 0, stream>>>(
            sents, entities, dense_w, hws, mws);
        bilinear_kernel<<<BATCH / BB, 256, 0, stream>>>(hws, mws, A, dense_b, out);
    } else {
        fused_kernel<<<BATCH, 256, 0, stream>>>(sents, entities, A, dense_w, dense_b, out);
    }
}